// Round 19
// baseline (252.289 us; speedup 1.0000x reference)
//
#include <hip/hip_runtime.h>
#include <stdint.h>
#include <math.h>

typedef unsigned short u16;
typedef __attribute__((ext_vector_type(4))) float f32x4;
typedef __attribute__((ext_vector_type(16))) float f32x16;
typedef __attribute__((ext_vector_type(8))) __bf16 bf16x8;

#define DEV static __device__ __forceinline__

typedef __attribute__((address_space(1))) void gvoid;
typedef __attribute__((address_space(3))) void lvoid;

DEV float bf2f(u16 u){ uint32_t v = ((uint32_t)u) << 16; float f; __builtin_memcpy(&f, &v, 4); return f; }
DEV u16 f2bf(float f){ uint32_t v; __builtin_memcpy(&v, &f, 4); v = (v + 0x7fffu + ((v >> 16) & 1u)) >> 16; return (u16)v; }

DEV void cp16(const void* g, void* l){
  __builtin_amdgcn_global_load_lds((gvoid*)g, (lvoid*)l, 16, 0, 0);
}
DEV f32x4 mfma16(bf16x8 a, bf16x8 b, f32x4 c){
  return __builtin_amdgcn_mfma_f32_16x16x32_bf16(a, b, c, 0, 0, 0);
}
DEV f32x16 mfma32(bf16x8 a, bf16x8 b, f32x16 c){
  return __builtin_amdgcn_mfma_f32_32x32x16_bf16(a, b, c, 0, 0, 0);
}
DEV uint32_t cvtpk(float a, float b){
  uint32_t r;
  asm volatile("v_cvt_pk_bf16_f32 %0, %1, %2" : "=v"(r) : "v"(a), "v"(b));
  return r;
}
DEV void uswap(uint32_t& a, uint32_t& b){
  asm volatile("v_permlane32_swap_b32 %0, %1" : "+v"(a), "+v"(b));
}
DEV void fswap(float& a, float& b){
  asm volatile("v_permlane32_swap_b32 %0, %1" : "+v"(a), "+v"(b));
}
DEV float fexp2(float x){
  float r;
  asm("v_exp_f32 %0, %1" : "=v"(r) : "v"(x));
  return r;
}

#define FENCE_BARRIER do { asm volatile("" ::: "memory"); __builtin_amdgcn_s_barrier(); } while (0)
#define WAIT_VM(n) asm volatile("s_waitcnt vmcnt(" #n ")" ::: "memory")

// 2D slab remap for XCD L2 locality. Grid (GX,GY) split into (GX/SX)x(GY/SY)
// slabs; XCD x (= hw_id&7) processes slabs x, x+8, ... sequentially.
// Requires (GX/SX)*(GY/SY) == 8 * slabs_per_xcd. Bijective.
DEV void slab_remap(int SX, int SY, int& bx, int& by)
{
  const int GX = gridDim.x;
  const int h = blockIdx.y * GX + blockIdx.x;
  const int x = h & 7, s = h >> 3;
  const int ssz = SX * SY;
  const int nsx = GX / SX;
  const int slab = x + 8 * (s / ssz);
  const int ws = s % ssz;
  bx = (slab % nsx) * SX + ws % SX;
  by = (slab / nsx) * SY + ws / SX;
}

// ---------------------------------------------------------------------------
// AdaLN: mods[b][6144] = silu(c[b]) @ adaln_w + adaln_b   (two-stage for ILP)
// ---------------------------------------------------------------------------
__global__ void __launch_bounds__(256) adaln1(const float* __restrict__ c,
                                              const float* __restrict__ w,
                                              float* __restrict__ part)
{
  __shared__ float sc[256]; // [2][128] silu(c) slice
  int k0 = blockIdx.y * 128;
  {
    int i = threadIdx.x;           // 256 threads cover 2*128
    int b = i >> 7, kk = i & 127;
    float v = c[b * 1024 + k0 + kk];
    sc[i] = v / (1.f + __expf(-v));
  }
  __syncthreads();
  int col = blockIdx.x * 256 + threadIdx.x;
  float a0 = 0.f, a1 = 0.f;
  #pragma unroll 8
  for (int k = 0; k < 128; ++k){
    float wv = w[(size_t)(k0 + k) * 6144 + col];
    a0 += sc[k] * wv;
    a1 += sc[128 + k] * wv;
  }
  part[((size_t)blockIdx.y * 2 + 0) * 6144 + col] = a0;
  part[((size_t)blockIdx.y * 2 + 1) * 6144 + col] = a1;
}

__global__ void __launch_bounds__(256) adaln2(const float* __restrict__ part,
                                              const float* __restrict__ bias,
                                              float* __restrict__ mods)
{
  int i = blockIdx.x * 256 + threadIdx.x;   // 2*6144
  int b = i / 6144, col = i % 6144;
  float a = bias[col];
  #pragma unroll
  for (int r = 0; r < 8; ++r) a += part[((size_t)r * 2 + b) * 6144 + col];
  mods[i] = a;
}

// ---------------------------------------------------------------------------
// RoPE table: ctab/stab[t*32+i] = cos/sin(pos[t] * 10000^(-i/32))
// ---------------------------------------------------------------------------
__global__ void __launch_bounds__(256) rope_table(const int* __restrict__ pos,
                                                  float* __restrict__ ct,
                                                  float* __restrict__ st)
{
  int idx = blockIdx.x * 256 + threadIdx.x;   // T*32 = 65536
  int t = idx >> 5, i = idx & 31;
  float freq = expf(-0.28782313662425575f * (float)i);  // ln(10000)/32
  float ang = (float)pos[t] * freq;
  ct[idx] = cosf(ang);
  st[idx] = sinf(ang);
}

// ---------------------------------------------------------------------------
// RMSNorm (no affine) + AdaLN modulate -> bf16.  One block per (b,t) row.
// ---------------------------------------------------------------------------
__global__ void __launch_bounds__(256) rmsmod(const float* __restrict__ x,
                                              const float* __restrict__ mods,
                                              u16* __restrict__ out,
                                              int shift_off, int scale_off)
{
  __shared__ float wsum[4];
  int row = blockIdx.x;            // b*2048 + t
  int b = row >> 11;
  const float4 v = ((const float4*)(x + (size_t)row * 1024))[threadIdx.x];
  float ss = v.x * v.x + v.y * v.y + v.z * v.z + v.w * v.w;
  #pragma unroll
  for (int m = 1; m < 64; m <<= 1) ss += __shfl_xor(ss, m);
  if ((threadIdx.x & 63) == 0) wsum[threadIdx.x >> 6] = ss;
  __syncthreads();
  float tot = wsum[0] + wsum[1] + wsum[2] + wsum[3];
  float rr = rsqrtf(tot * (1.f / 1024.f) + 1e-6f);
  const float* mb = mods + (size_t)b * 6144;
  int d0 = threadIdx.x * 4;
  ushort4 o;
  o.x = f2bf(v.x * rr * (1.f + mb[scale_off + d0 + 0]) + mb[shift_off + d0 + 0]);
  o.y = f2bf(v.y * rr * (1.f + mb[scale_off + d0 + 1]) + mb[shift_off + d0 + 1]);
  o.z = f2bf(v.z * rr * (1.f + mb[scale_off + d0 + 2]) + mb[shift_off + d0 + 2]);
  o.w = f2bf(v.w * rr * (1.f + mb[scale_off + d0 + 3]) + mb[shift_off + d0 + 3]);
  ((ushort4*)(out + (size_t)row * 1024))[threadIdx.x] = o;
}

// ---------------------------------------------------------------------------
// Weight transpose + cast: in f32 [R][C] -> out bf16 [C][R].
// Store phase vectorized: each thread writes ushort2 (2 consecutive R cols)
// -- scalar 2B stores were half-rate on the write port (G13).
// ---------------------------------------------------------------------------
__global__ void __launch_bounds__(256) transpose_w(const float* __restrict__ in,
                                                   u16* __restrict__ out, int R, int C)
{
  __shared__ float t[32][33];
  int tx = threadIdx.x & 31, ty = threadIdx.x >> 5;
  int c0 = blockIdx.x * 32, r0 = blockIdx.y * 32;
  #pragma unroll
  for (int i = 0; i < 4; ++i) t[ty + 8 * i][tx] = in[(size_t)(r0 + ty + 8 * i) * C + c0 + tx];
  __syncthreads();
  int px = threadIdx.x & 15;        // col-pair: r = r0 + 2*px, 2*px+1
  int py = threadIdx.x >> 4;        // 16 output rows per iter
  #pragma unroll
  for (int i = 0; i < 2; ++i) {
    int cc = py + 16 * i;           // 0..31 output rows (c-dim)
    ushort2 v;
    v.x = f2bf(t[2 * px + 0][cc]);
    v.y = f2bf(t[2 * px + 1][cc]);
    *(ushort2*)(out + (size_t)(c0 + cc) * R + r0 + 2 * px) = v;
  }
}

// ---------------------------------------------------------------------------
// V transpose: qkv bf16 [B,T,3D] (v slice) -> vt bf16 [B,H,Dh,T].
// Load AND store phases vectorized to ushort2 (scalar 2B was half-rate).
// ---------------------------------------------------------------------------
__global__ void __launch_bounds__(256) vtrans(const u16* __restrict__ qkv,
                                              u16* __restrict__ vt)
{
  __shared__ u16 tile[32][33];
  int px = threadIdx.x & 15, py = threadIdx.x >> 4;   // 16x16 threads
  int t0 = blockIdx.x * 32;
  int d0 = blockIdx.y * 32;
  int bh = blockIdx.z; int b = bh >> 4, h = bh & 15;
  #pragma unroll
  for (int i = 0; i < 2; ++i) {
    int t = py + 16 * i;            // 32 t rows; d pairs 2*px
    ushort2 v = *(const ushort2*)(qkv + ((size_t)(b * 2048 + t0 + t)) * 3072
                                  + 2048 + h * 64 + d0 + 2 * px);
    tile[t][2 * px + 0] = v.x;
    tile[t][2 * px + 1] = v.y;
  }
  __syncthreads();
  #pragma unroll
  for (int i = 0; i < 2; ++i) {
    int d = py + 16 * i;            // 32 d rows; t pairs 2*px
    ushort2 v;
    v.x = tile[2 * px + 0][d];
    v.y = tile[2 * px + 1][d];
    *(ushort2*)(vt + ((size_t)bh * 64 + d0 + d) * 2048 + t0 + 2 * px) = v;
  }
}

// ---------------------------------------------------------------------------
// GEMM (qkv): C[M,N] = A * Bt^T, bf16 out. r7-proven geometry: 128x128,
// BK=64, SINGLE-buffered 32KB LDS, 2 barriers/K-step, 8-chunk swizzle,
// slab-remapped blocks.
// ---------------------------------------------------------------------------
__global__ void __launch_bounds__(256) gemm_bt(const u16* __restrict__ A,
                                               const u16* __restrict__ Bt,
                                               int M, int N, int K,
                                               int SX, int SY,
                                               u16* __restrict__ outb)
{
  __shared__ __align__(16) u16 Ash[128 * 64];   // 16KB
  __shared__ __align__(16) u16 Bsh[128 * 64];   // 16KB
  const int tid = threadIdx.x;
  const int l = tid & 63, w = tid >> 6;
  int bx, by; slab_remap(SX, SY, bx, by);
  const int m0 = by * 128, n0 = bx * 128;
  const int wr = (w >> 1) * 64, wc = (w & 1) * 64;
  const int fr = l & 15, fg = l >> 4;
  const int sw = fr & 7;
  f32x4 acc[4][4] = {};

  for (int kt = 0; kt < K; kt += 64) {
    __syncthreads();
    #pragma unroll
    for (int p = 0; p < 4; ++p) {
      int slot = p * 256 + tid;           // 0..1023
      int r = slot >> 3, kp = slot & 7;
      int kpg = kp ^ (r & 7);             // pre-swizzled source chunk (rule #21)
      cp16(A + (size_t)(m0 + r) * K + kt + kpg * 8, Ash + slot * 8);
      cp16(Bt + (size_t)(n0 + r) * K + kt + kpg * 8, Bsh + slot * 8);
    }
    __syncthreads();
    #pragma unroll
    for (int kk = 0; kk < 2; ++kk) {
      const int coff = ((kk * 4 + fg) ^ sw) * 8;   // swizzled 16B chunk within row
      bf16x8 af[4], bfr[4];
      #pragma unroll
      for (int m = 0; m < 4; ++m) af[m] = *(const bf16x8*)(Ash + (wr + m * 16 + fr) * 64 + coff);
      #pragma unroll
      for (int n = 0; n < 4; ++n) bfr[n] = *(const bf16x8*)(Bsh + (wc + n * 16 + fr) * 64 + coff);
      #pragma unroll
      for (int m = 0; m < 4; ++m)
        #pragma unroll
        for (int n = 0; n < 4; ++n)
          acc[m][n] = mfma16(af[m], bfr[n], acc[m][n]);
    }
  }

  #pragma unroll
  for (int m = 0; m < 4; ++m)
  #pragma unroll
  for (int n = 0; n < 4; ++n)
  #pragma unroll
  for (int j = 0; j < 4; ++j) {
    int row = m0 + wr + m * 16 + fg * 4 + j;
    int col = n0 + wc + n * 16 + fr;
    outb[(size_t)row * N + col] = f2bf(acc[m][n][j]);
  }
}

// ---------------------------------------------------------------------------
// Skinny GEMM for N=1024 outputs (proj, w2): BM=64 x BN=128, BK=64, dbuf LDS,
// slab-remapped (params). EPI: 1 = res + gate*(C+bias); 4 = res + gate*C.
// ---------------------------------------------------------------------------
template<int EPI>
__global__ void __launch_bounds__(256) gemm_skinny(const u16* __restrict__ A,
                                                   const u16* __restrict__ Bt,
                                                   int M, int N, int K,
                                                   int SX, int SY,
                                                   const float* __restrict__ mods,
                                                   int gate_off,
                                                   const float* __restrict__ bias,
                                                   const float* __restrict__ res,
                                                   float* __restrict__ outf)
{
  __shared__ __align__(16) u16 Ash[2][64 * 64];    // 16KB
  __shared__ __align__(16) u16 Bsh[2][128 * 64];   // 32KB
  const int tid = threadIdx.x;
  const int l = tid & 63, w = tid >> 6;
  int bx, by; slab_remap(SX, SY, bx, by);
  const int m0 = by * 64, n0 = bx * 128;
  const int wr = (w >> 1) * 32, wc = (w & 1) * 64;
  const int fr = l & 15, fg = l >> 4;
  const int sw = fr & 7;
  const int nk = K >> 6;
  f32x4 acc[2][4] = {};

  auto stage = [&](int kt, int bsel) {
    #pragma unroll
    for (int p = 0; p < 2; ++p) {
      int slot = p * 256 + tid;            // 0..511 (A rows 0..63)
      int r = slot >> 3, kp = slot & 7;
      int kpg = kp ^ (r & 7);
      cp16(A + (size_t)(m0 + r) * K + kt + kpg * 8, &Ash[bsel][slot * 8]);
    }
    #pragma unroll
    for (int p = 0; p < 4; ++p) {
      int slot = p * 256 + tid;            // 0..1023 (B rows 0..127)
      int r = slot >> 3, kp = slot & 7;
      int kpg = kp ^ (r & 7);
      cp16(Bt + (size_t)(n0 + r) * K + kt + kpg * 8, &Bsh[bsel][slot * 8]);
    }
  };

  stage(0, 0);
  __syncthreads();

  for (int t = 0; t < nk; ++t) {
    if (t + 1 < nk) stage((t + 1) << 6, (t + 1) & 1);
    const u16* Ab = Ash[t & 1];
    const u16* Bb = Bsh[t & 1];
    #pragma unroll
    for (int kk = 0; kk < 2; ++kk) {
      const int coff = ((kk * 4 + fg) ^ sw) * 8;
      bf16x8 af[2], bfr[4];
      #pragma unroll
      for (int m = 0; m < 2; ++m) af[m] = *(const bf16x8*)(Ab + (wr + m * 16 + fr) * 64 + coff);
      #pragma unroll
      for (int n = 0; n < 4; ++n) bfr[n] = *(const bf16x8*)(Bb + (wc + n * 16 + fr) * 64 + coff);
      #pragma unroll
      for (int m = 0; m < 2; ++m)
        #pragma unroll
        for (int n = 0; n < 4; ++n)
          acc[m][n] = mfma16(af[m], bfr[n], acc[m][n]);
    }
    __syncthreads();   // drains stage(t+1) (hidden under compute) + WAR
  }

  #pragma unroll
  for (int m = 0; m < 2; ++m)
  #pragma unroll
  for (int n = 0; n < 4; ++n)
  #pragma unroll
  for (int j = 0; j < 4; ++j) {
    int row = m0 + wr + m * 16 + fg * 4 + j;
    int col = n0 + wc + n * 16 + fr;
    size_t idx = (size_t)row * N + col;
    float v = acc[m][n][j];
    int b = row >> 11;
    if (EPI == 1)
      outf[idx] = res[idx] + mods[(size_t)b * 6144 + gate_off + col] * (v + bias[col]);
    else
      outf[idx] = res[idx] + mods[(size_t)b * 6144 + gate_off + col] * v;
  }
}

// ---------------------------------------------------------------------------
// 1-barrier-per-tile counted-vmcnt SwiGLU GEMM (r18 best, 63.5us):
// BM=256, BN=128/product, BK=64, 8 waves, 128KB dbuf LDS, slab (11,2).
// Full next-tile prefetch (8 loads), WAIT_VM(8) (never 0), one s_barrier,
// then two unbarriered half-phases with compiler-scheduled lgkmcnt.
// ---------------------------------------------------------------------------
__global__ void __launch_bounds__(512) gemm_w13(const u16* __restrict__ A,
                                                const u16* __restrict__ B1t,
                                                const u16* __restrict__ B3t,
                                                u16* __restrict__ outb)
{
  const int K = 1024, N = 2816, NK = 16;   // K / 64
  __shared__ __align__(16) char smem[131072];  // [2][A 32KB | B1 16KB | B3 16KB]
  const int tid = threadIdx.x;             // 0..511
  const int l = tid & 63, w = tid >> 6;    // 8 waves
  const int wm = w >> 1, wn = w & 1;       // 4M x 2N
  int bx, by; slab_remap(11, 2, bx, by);
  const int m0 = by * 256, n0 = bx * 128;
  const int fr = l & 15, fg = l >> 4;

  const int r0 = tid >> 3, cl = tid & 7;
  const int cg = cl ^ (r0 & 7);
  const size_t aoffA0_0 = (size_t)(m0 + r0) * K + cg * 8;
  const size_t aoffA0_1 = (size_t)(m0 + 64 + r0) * K + cg * 8;
  const size_t aoffA1_0 = (size_t)(m0 + 128 + r0) * K + cg * 8;
  const size_t aoffA1_1 = (size_t)(m0 + 192 + r0) * K + cg * 8;
  const size_t boff_0   = (size_t)(n0 + r0) * K + cg * 8;
  const size_t boff_1   = (size_t)(n0 + 64 + r0) * K + cg * 8;
  const int lds0 = tid * 16, lds1 = (512 + tid) * 16;   // within a 16KB half

  const int co0 = ((0 * 4 + fg) ^ (fr & 7)) << 4;   // kk=0 chunk byte off
  const int co1 = ((1 * 4 + fg) ^ (fr & 7)) << 4;   // kk=1
  int rA[4], rB[4];
  #pragma unroll
  for (int m = 0; m < 4; ++m) rA[m] = (wm * 64 + m * 16 + fr) * 128;
  #pragma unroll
  for (int n = 0; n < 4; ++n) rB[n] = (wn * 64 + n * 16 + fr) * 128;

  f32x4 acc1[4][4] = {}, acc3[4][4] = {};

  auto stA0 = [&](int kt, int buf){
    char* d = smem + buf * 65536;
    cp16(A + aoffA0_0 + kt, d + lds0);
    cp16(A + aoffA0_1 + kt, d + lds1);
  };
  auto stA1 = [&](int kt, int buf){
    char* d = smem + buf * 65536 + 16384;
    cp16(A + aoffA1_0 + kt, d + lds0);
    cp16(A + aoffA1_1 + kt, d + lds1);
  };
  auto stB1 = [&](int kt, int buf){
    char* d = smem + buf * 65536 + 32768;
    cp16(B1t + boff_0 + kt, d + lds0);
    cp16(B1t + boff_1 + kt, d + lds1);
  };
  auto stB3 = [&](int kt, int buf){
    char* d = smem + buf * 65536 + 49152;
    cp16(B3t + boff_0 + kt, d + lds0);
    cp16(B3t + boff_1 + kt, d + lds1);
  };

  // prologue: tile 0 -> buffer 0 (8 loads in flight, steady-state invariant)
  stA0(0, 0); stA1(0, 0); stB1(0, 0); stB3(0, 0);

  for (int t = 0; t < NK; ++t) {
    const int buf = t & 1, nbuf = buf ^ 1;
    const int ktn = ((t + 1) & (NK - 1)) * 64;
    const char* Ab  = smem + buf * 65536;          // A0 | A1 contiguous 32KB
    const char* B1b = smem + buf * 65536 + 32768;
    const char* B3b = smem + buf * 65536 + 49152;

    // issue the FULL next-tile prefetch (8 loads -> 16 in flight)
    stA0(ktn, nbuf); stA1(ktn, nbuf); stB1(ktn, nbuf); stB3(ktn, nbuf);
    WAIT_VM(8);      // drains exactly tile t's 8 loads; t+1's stay in flight
    FENCE_BARRIER;   // all waves' tile-t data visible

    bf16x8 af0[4], af1[4];
    #pragma unroll
    for (int m = 0; m < 4; ++m) af0[m] = *(const bf16x8*)(Ab + rA[m] + co0);
    #pragma unroll
    for (int m = 0; m < 4; ++m) af1[m] = *(const bf16x8*)(Ab + rA[m] + co1);

    // ---- half-phase 1: acc1 (A x B1), kk=0 and kk=1 ----
    {
      bf16x8 b0[4], b1[4];
      #pragma unroll
      for (int n = 0; n < 4; ++n) b0[n] = *(const bf16x8*)(B1b + rB[n] + co0);
      #pragma unroll
      for (int n = 0; n < 4; ++n) b1[n] = *(const bf16x8*)(B1b + rB[n] + co1);
      __builtin_amdgcn_s_setprio(1);
      #pragma unroll
      for (int m = 0; m < 4; ++m)
        #pragma unroll
        for (int n = 0; n < 4; ++n) acc1[m][n] = mfma16(af0[m], b0[n], acc1[m][n]);
      #pragma unroll
      for (int m = 0; m < 4; ++m)
        #pragma unroll
        for (int n = 0; n < 4; ++n) acc1[m][n] = mfma16(af1[m], b1[n], acc1[m][n]);
      __builtin_amdgcn_s_setprio(0);
    }

    // ---- half-phase 2: acc3 (A x B3); A-frags still live ----
    {
      bf16x8 b0[4], b1[4];
      #pragma unroll
      for (int n = 0; n < 4; ++n) b0[n] = *(const bf16x8*)(B3b + rB[n] + co0);
      #pragma unroll
      for (int n = 0; n < 4; ++n) b1[n] = *(const bf16x8*)(B3b + rB[n] + co1);
      __builtin_amdgcn_s_setprio(1);
      #pragma unroll
      for (int m = 0; m < 4; ++m)
        #pragma unroll
        for (int n = 0; n < 4; ++n) acc3[m][n] = mfma16(af0[m], b0[n], acc3[m][n]);
      #pragma unroll
      for (int m = 0; m < 4; ++m)
        #pragma unroll
        for (int n = 0; n < 4; ++n) acc3[m][n] = mfma16(af1[m], b1[n], acc3[m][n]);
      __builtin_amdgcn_s_setprio(0);
    }
  }

  // epilogue: silu(acc1)*acc3, pairing in-thread; direct global store
  #pragma unroll
  for (int m = 0; m < 4; ++m)
  #pragma unroll
  for (int n = 0; n < 4; ++n)
  #pragma unroll
  for (int j = 0; j < 4; ++j) {
    int row = m0 + wm * 64 + m * 16 + fg * 4 + j;
    int col = n0 + wn * 64 + n * 16 + fr;
    float v1 = acc1[m][n][j];
    float v3 = acc3[m][n][j];
    float s = v1 / (1.f + __expf(-v1));
    outb[(size_t)row * N + col] = f2bf(s * v3);
  }
}

// ---------------------------------------------------------------------------
// qk-norm (per-head RMS, affine) + RoPE.
// qkv bf16 [B,T,3D] -> q/k bf16 [B,H,T,Dh]; q pre-scaled by log2(e)/sqrt(Dh).
// ---------------------------------------------------------------------------
__global__ void __launch_bounds__(256) qknorm_rope(const u16* __restrict__ qkv,
                                                   const float* __restrict__ lnq,
                                                   const float* __restrict__ lnk,
                                                   const float* __restrict__ ctab,
                                                   const float* __restrict__ stab,
                                                   u16* __restrict__ qo,
                                                   u16* __restrict__ ko)
{
  int r = blockIdx.x * 4 + (threadIdx.x >> 6);   // (b*2048 + t)*16 + h
  int l = threadIdx.x & 63;
  int h = r & 15, t = (r >> 4) & 2047, b = r >> 15;
  const u16* base = qkv + ((size_t)(b * 2048 + t)) * 3072 + h * 64 + l;
  float q = bf2f(base[0]);
  float k = bf2f(base[1024]);
  float sq = q * q, sk = k * k;
  #pragma unroll
  for (int m = 1; m < 64; m <<= 1) { sq += __shfl_xor(sq, m); sk += __shfl_xor(sk, m); }
  float rq = rsqrtf(sq * (1.f / 64.f) + 1e-6f);
  float rk = rsqrtf(sk * (1.f / 64.f) + 1e-6f);
  float yq = q * rq * lnq[l];
  float yk = k * rk * lnk[l];
  float cs = ctab[t * 32 + (l & 31)];
  float sn = stab[t * 32 + (l & 31)];
  float pq = __shfl_xor(yq, 32);
  float pk = __shfl_xor(yk, 32);
  float rotq = (l < 32) ? -pq : pq;
  float rotk = (l < 32) ? -pk : pk;
  float oq = (yq * cs + rotq * sn) * 0.1803368801111204f;  // (1/8)*log2(e)
  float ok = yk * cs + rotk * sn;
  size_t oidx = ((size_t)(b * 16 + h) * 2048 + t) * 64 + l;
  qo[oidx] = f2bf(oq);
  ko[oidx] = f2bf(ok);
}

// ---------------------------------------------------------------------------
// Flash attention, 32x32 swapped-QK^T, MAX-FREE softmax (|q.k|/8 <= 8 after
// qk-norm + norm-preserving RoPE -> exp2 args bounded; no running max).
// KVBLK=128, K/V dbuf in LDS via async global_load_lds; XOR-chunk swizzle
// staged on the GLOBAL source (rule #21). XCD-aware block remap.
// ---------------------------------------------------------------------------
__global__ void __launch_bounds__(256, 2) flash_attn(const u16* __restrict__ qg,
                                                     const u16* __restrict__ kg,
                                                     const u16* __restrict__ vtg,
                                                     u16* __restrict__ og)
{
  __shared__ __align__(16) char smem[65536];
  const int tid = threadIdx.x, l = tid & 63, w = tid >> 6;
  const int lq = l & 31, hi = l >> 5;
  const int swz = lq & 7;
  const int xcd = blockIdx.x & 7, slot = blockIdx.x >> 3;
  const int g = slot >> 4, qt = slot & 15;
  const int bh = g * 8 + xcd;
  const int h = bh & 15, b = bh >> 4;

  bf16x8 qf[4];
  {
    const u16* qp = qg + ((size_t)bh * 2048 + qt * 128 + w * 32 + lq) * 64 + hi * 8;
    #pragma unroll
    for (int ks = 0; ks < 4; ++ks) qf[ks] = *(const bf16x8*)(qp + ks * 16);
  }
  const u16* kgb = kg + (size_t)bh * 2048 * 64;
  const u16* vgb = vtg + (size_t)bh * 64 * 2048;

  auto stage = [&](int kv, int bsel) {
    #pragma unroll
    for (int p = 0; p < 4; ++p) {
      int s2 = p * 256 + tid;            // 0..1023
      int r = s2 >> 3, cl = s2 & 7;
      int cg = cl ^ (r & 7);
      cp16(kgb + (size_t)(kv + r) * 64 + cg * 8, smem + bsel * 16384 + s2 * 16);
    }
    #pragma unroll
    for (int p = 0; p < 4; ++p) {
      int s2 = p * 256 + tid;            // 0..1023
      int r = s2 >> 4, cl = s2 & 15;
      int cg = cl ^ (r & 7);
      cp16(vgb + (size_t)r * 2048 + kv + cg * 8, smem + 32768 + bsel * 16384 + s2 * 16);
    }
  };

  f32x16 ob0 = {}, ob1 = {};
  float l_run = 0.f;

  stage(0, 0);
  __syncthreads();

  for (int t = 0; t < 16; ++t) {
    const int cur = t & 1;
    stage(((t + 1) & 15) * 128, cur ^ 1);   // async prefetch next tile
    const char* Kb = smem + cur * 16384;
    const char* Vb = smem + 32768 + cur * 16384;

    #pragma unroll
    for (int ko = 0; ko < 128; ko += 64) {
      f32x16 s0 = {}, s1 = {};
      __builtin_amdgcn_s_setprio(1);
      #pragma unroll
      for (int ks = 0; ks < 4; ++ks) {
        const int c = hi + ks * 2;
        bf16x8 kf0 = *(const bf16x8*)(Kb + (ko + lq) * 128 + ((c ^ swz) << 4));
        bf16x8 kf1 = *(const bf16x8*)(Kb + (ko + 32 + lq) * 128 + ((c ^ swz) << 4));
        s0 = mfma32(kf0, qf[ks], s0);
        s1 = mfma32(kf1, qf[ks], s1);
      }
      __builtin_amdgcn_s_setprio(0);
      #pragma unroll
      for (int r = 0; r < 16; ++r) s0[r] = fexp2(s0[r]);
      #pragma unroll
      for (int r = 0; r < 16; ++r) s1[r] = fexp2(s1[r]);
      {
        float t0 = (s0[0] + s0[1]) + (s0[2] + s0[3]);
        float t1 = (s0[4] + s0[5]) + (s0[6] + s0[7]);
        float t2 = (s0[8] + s0[9]) + (s0[10] + s0[11]);
        float t3 = (s0[12] + s0[13]) + (s0[14] + s0[15]);
        float u0 = (s1[0] + s1[1]) + (s1[2] + s1[3]);
        float u1 = (s1[4] + s1[5]) + (s1[6] + s1[7]);
        float u2 = (s1[8] + s1[9]) + (s1[10] + s1[11]);
        float u3 = (s1[12] + s1[13]) + (s1[14] + s1[15]);
        float ls = ((t0 + t1) + (t2 + t3)) + ((u0 + u1) + (u2 + u3));
        float lo = ls;
        fswap(ls, lo);
        l_run += ls + lo;
      }
      uint32_t pw[16];
      {
        uint32_t x0 = cvtpk(s0[0], s0[1]),   y0 = cvtpk(s0[4], s0[5]);   uswap(x0, y0);
        uint32_t x1 = cvtpk(s0[2], s0[3]),   y1 = cvtpk(s0[6], s0[7]);   uswap(x1, y1);
        uint32_t x2 = cvtpk(s0[8], s0[9]),   y2 = cvtpk(s0[12], s0[13]); uswap(x2, y2);
        uint32_t x3 = cvtpk(s0[10], s0[11]), y3 = cvtpk(s0[14], s0[15]); uswap(x3, y3);
        pw[0] = x0; pw[1] = x1; pw[2] = y0; pw[3] = y1;
        pw[4] = x2; pw[5] = x3; pw[6] = y2; pw[7] = y3;
      }
      {
        uint32_t x0 = cvtpk(s1[0], s1[1]),   y0 = cvtpk(s1[4], s1[5]);   uswap(x0, y0);
        uint32_t x1 = cvtpk(s1[2], s1[3]),   y1 = cvtpk(s1[6], s1[7]);   uswap(x1, y1);
        uint32_t x2 = cvtpk(s1[8], s1[9]),   y2 = cvtpk(s1[12], s1[13]); uswap(x2, y2);
        uint32_t x3 = cvtpk(s1[10], s1[11]), y3 = cvtpk(s1[14], s1[15]); uswap(x3, y3);
        pw[8] = x0;  pw[9] = x1;  pw[10] = y0; pw[11] = y1;
        pw[12] = x2; pw[13] = x3; pw[14] = y2; pw[15] = y3;
      }
      __builtin_amdgcn_s_setprio(1);
      #pragma unroll
      for (int ks = 0; ks < 4; ++ks) {
        union { uint32_t u[4]; bf16x8 v; } pk_;
        pk_.u[0] = pw[ks * 4 + 0]; pk_.u[1] = pw[ks * 4 + 1];
        pk_.u[2] = pw[ks * 4 + 2]; pk_.u[3] = pw[ks * 4 + 3];
        const int c = (ko >> 3) + ks * 2 + hi;
        bf16x8 vf0 = *(const bf16x8*)(Vb + lq * 256 + ((c ^ swz) << 4));
        bf16x8 vf1 = *(const bf16x8*)(Vb + (32 + lq) * 256 + ((c ^ swz) << 4));
        ob0 = mfma32(vf0, pk_.v, ob0);
        ob1 = mfma32(vf1, pk_.v, ob1);
      }
      __builtin_amdgcn_s_setprio(0);
    }
    __syncthreads();
  }

  float invl = 1.0f / l_run;
  char* ob_base = smem + w * 4096 + lq * 128 + 8 * hi;
  #pragma unroll
  for (int g2 = 0; g2 < 4; ++g2) {
    uint2 t2;
    t2.x = cvtpk(ob0[g2 * 4 + 0] * invl, ob0[g2 * 4 + 1] * invl);
    t2.y = cvtpk(ob0[g2 * 4 + 2] * invl, ob0[g2 * 4 + 3] * invl);
    *(uint2*)(ob_base + ((g2 ^ (lq & 7)) << 4)) = t2;
    uint2 t3;
    t3.x = cvtpk(ob1[g2 * 4 + 0] * invl, ob1[g2 * 4 + 1] * invl);
    t3.y = cvtpk(ob1[g2 * 4 + 2] * invl, ob1[g2 * 4 + 3] * invl);
    *(uint2*)(ob_base + (((g2 + 4) ^ (lq & 7)) << 4)) = t3;
  }
  __syncthreads();
  #pragma unroll
  for (int i = 0; i < 4; ++i) {
    int idx = i * 256 + tid;
    int ww = idx >> 8, q = (idx >> 3) & 31, s = idx & 7;
    uint4 val = *(const uint4*)(smem + ww * 4096 + q * 128 + ((s ^ (q & 7)) << 4));
    int t = qt * 128 + ww * 32 + q;
    *(uint4*)(og + ((size_t)(b * 2048 + t)) * 1024 + h * 64 + s * 8) = val;
  }
}

// ---------------------------------------------------------------------------
extern "C" void kernel_launch(void* const* d_in, const int* in_sizes, int n_in,
                              void* d_out, int out_size, void* d_ws, size_t ws_size,
                              hipStream_t stream)
{
  (void)in_sizes; (void)n_in; (void)out_size; (void)ws_size;
  const float* x       = (const float*)d_in[0];
  const float* c       = (const float*)d_in[1];
  const int*   pos     = (const int*)d_in[2];
  const float* adaln_w = (const float*)d_in[3];
  const float* adaln_b = (const float*)d_in[4];
  const float* qkv_w   = (const float*)d_in[5];
  const float* lnq     = (const float*)d_in[6];
  const float* lnk     = (const float*)d_in[7];
  const float* proj_w  = (const float*)d_in[8];
  const float* proj_b  = (const float*)d_in[9];
  const float* w1_w    = (const float*)d_in[10];
  const float* w3_w    = (const float*)d_in[11];
  const float* w2_w    = (const float*)d_in[12];
  float* out = (float*)d_out;

  char* ws = (char*)d_ws;
  size_t off = 0;
  auto alloc = [&](size_t bytes) -> char* {
    char* p = ws + off; off += (bytes + 255) & ~(size_t)255; return p;
  };
  float* part    = (float*)alloc((size_t)8 * 2 * 6144 * 4);
  float* mods    = (float*)alloc((size_t)2 * 6144 * 4);
  float* ctab    = (float*)alloc((size_t)2048 * 32 * 4);
  float* stab    = (float*)alloc((size_t)2048 * 32 * 4);
  u16* qkv_wt    = (u16*)alloc((size_t)3072 * 1024 * 2);
  u16* proj_wt   = (u16*)alloc((size_t)1024 * 1024 * 2);
  u16* w1_wt     = (u16*)alloc((size_t)2816 * 1024 * 2);
  u16* w3_wt     = (u16*)alloc((size_t)2816 * 1024 * 2);
  u16* w2_wt     = (u16*)alloc((size_t)1024 * 2816 * 2);
  float* x1      = (float*)alloc((size_t)4096 * 1024 * 4);
  u16* attn_bf   = (u16*)alloc((size_t)4096 * 1024 * 2);
  char* pool = ws + off;   // phase-aliased region
  // phase A
  u16* xmod_bf   = (u16*)(pool);
  u16* qkv_bf    = (u16*)(pool + 8388608);
  u16* q_bf      = (u16*)(pool + 33554432);
  u16* k_bf      = (u16*)(pool + 41943040);
  u16* vt_bf     = (u16*)(pool + 50331648);
  // phase B (aliases phase A, which is dead by then)
  u16* h_bf      = (u16*)(pool);
  u16* hidden_bf = (u16*)(pool + 31457280);

  adaln1<<<dim3(24, 8), 256, 0, stream>>>(c, adaln_w, part);
  adaln2<<<48, 256, 0, stream>>>(part, adaln_b, mods);
  rope_table<<<256, 256, 0, stream>>>(pos, ctab, stab);
  rmsmod<<<4096, 256, 0, stream>>>(x, mods, xmod_bf, 0, 1024);
  transpose_w<<<dim3(96, 32), 256, 0, stream>>>(qkv_w, qkv_wt, 1024, 3072);
  transpose_w<<<dim3(32, 32), 256, 0, stream>>>(proj_w, proj_wt, 1024, 1024);
  transpose_w<<<dim3(88, 32), 256, 0, stream>>>(w1_w, w1_wt, 1024, 2816);
  transpose_w<<<dim3(88, 32), 256, 0, stream>>>(w3_w, w3_wt, 1024, 2816);
  transpose_w<<<dim3(32, 88), 256, 0, stream>>>(w2_w, w2_wt, 2816, 1024);

  gemm_bt<<<dim3(24, 32), 256, 0, stream>>>(xmod_bf, qkv_wt, 4096, 3072, 1024, 6, 8, qkv_bf);
  qknorm_rope<<<16384, 256, 0, stream>>>(qkv_bf, lnq, lnk, ctab, stab, q_bf, k_bf);
  vtrans<<<dim3(64, 2, 32), 256, 0, stream>>>(qkv_bf, vt_bf);
  flash_attn<<<512, 256, 0, stream>>>(q_bf, k_bf, vt_bf, attn_bf);
  gemm_skinny<1><<<dim3(8, 64), 256, 0, stream>>>(attn_bf, proj_wt, 4096, 1024, 1024,
                                                  2, 4, mods, 2048, proj_b, x, x1);
  rmsmod<<<4096, 256, 0, stream>>>(x1, mods, h_bf, 3072, 4096);
  gemm_w13<<<dim3(22, 16), 512, 0, stream>>>(h_bf, w1_wt, w3_wt, hidden_bf);
  gemm_skinny<4><<<dim3(8, 64), 256, 0, stream>>>(hidden_bf, w2_wt, 4096, 1024, 2816,
                                                  2, 4, mods, 5120, nullptr, x1, out);
}

// Round 20
// 248.168 us; speedup vs baseline: 1.0166x; 1.0166x over previous
//
#include <hip/hip_runtime.h>
#include <stdint.h>
#include <math.h>

typedef unsigned short u16;
typedef __attribute__((ext_vector_type(4))) float f32x4;
typedef __attribute__((ext_vector_type(16))) float f32x16;
typedef __attribute__((ext_vector_type(8))) __bf16 bf16x8;

#define DEV static __device__ __forceinline__

typedef __attribute__((address_space(1))) void gvoid;
typedef __attribute__((address_space(3))) void lvoid;

DEV float bf2f(u16 u){ uint32_t v = ((uint32_t)u) << 16; float f; __builtin_memcpy(&f, &v, 4); return f; }
DEV u16 f2bf(float f){ uint32_t v; __builtin_memcpy(&v, &f, 4); v = (v + 0x7fffu + ((v >> 16) & 1u)) >> 16; return (u16)v; }

DEV void cp16(const void* g, void* l){
  __builtin_amdgcn_global_load_lds((gvoid*)g, (lvoid*)l, 16, 0, 0);
}
DEV f32x4 mfma16(bf16x8 a, bf16x8 b, f32x4 c){
  return __builtin_amdgcn_mfma_f32_16x16x32_bf16(a, b, c, 0, 0, 0);
}
DEV f32x16 mfma32(bf16x8 a, bf16x8 b, f32x16 c){
  return __builtin_amdgcn_mfma_f32_32x32x16_bf16(a, b, c, 0, 0, 0);
}
DEV uint32_t cvtpk(float a, float b){
  uint32_t r;
  asm volatile("v_cvt_pk_bf16_f32 %0, %1, %2" : "=v"(r) : "v"(a), "v"(b));
  return r;
}
DEV void uswap(uint32_t& a, uint32_t& b){
  asm volatile("v_permlane32_swap_b32 %0, %1" : "+v"(a), "+v"(b));
}
DEV void fswap(float& a, float& b){
  asm volatile("v_permlane32_swap_b32 %0, %1" : "+v"(a), "+v"(b));
}
DEV float fexp2(float x){
  float r;
  asm("v_exp_f32 %0, %1" : "=v"(r) : "v"(x));
  return r;
}

#define FENCE_BARRIER do { asm volatile("" ::: "memory"); __builtin_amdgcn_s_barrier(); } while (0)
#define WAIT_VM(n) asm volatile("s_waitcnt vmcnt(" #n ")" ::: "memory")

// 2D slab remap for XCD L2 locality. Grid (GX,GY) split into (GX/SX)x(GY/SY)
// slabs; XCD x (= hw_id&7) processes slabs x, x+8, ... sequentially.
// Requires (GX/SX)*(GY/SY) == 8 * slabs_per_xcd. Bijective.
DEV void slab_remap(int SX, int SY, int& bx, int& by)
{
  const int GX = gridDim.x;
  const int h = blockIdx.y * GX + blockIdx.x;
  const int x = h & 7, s = h >> 3;
  const int ssz = SX * SY;
  const int nsx = GX / SX;
  const int slab = x + 8 * (s / ssz);
  const int ws = s % ssz;
  bx = (slab % nsx) * SX + ws % SX;
  by = (slab / nsx) * SY + ws / SX;
}

// ---------------------------------------------------------------------------
// AdaLN: mods[b][6144] = silu(c[b]) @ adaln_w + adaln_b   (two-stage for ILP)
// ---------------------------------------------------------------------------
__global__ void __launch_bounds__(256) adaln1(const float* __restrict__ c,
                                              const float* __restrict__ w,
                                              float* __restrict__ part)
{
  __shared__ float sc[256]; // [2][128] silu(c) slice
  int k0 = blockIdx.y * 128;
  {
    int i = threadIdx.x;           // 256 threads cover 2*128
    int b = i >> 7, kk = i & 127;
    float v = c[b * 1024 + k0 + kk];
    sc[i] = v / (1.f + __expf(-v));
  }
  __syncthreads();
  int col = blockIdx.x * 256 + threadIdx.x;
  float a0 = 0.f, a1 = 0.f;
  #pragma unroll 8
  for (int k = 0; k < 128; ++k){
    float wv = w[(size_t)(k0 + k) * 6144 + col];
    a0 += sc[k] * wv;
    a1 += sc[128 + k] * wv;
  }
  part[((size_t)blockIdx.y * 2 + 0) * 6144 + col] = a0;
  part[((size_t)blockIdx.y * 2 + 1) * 6144 + col] = a1;
}

__global__ void __launch_bounds__(256) adaln2(const float* __restrict__ part,
                                              const float* __restrict__ bias,
                                              float* __restrict__ mods)
{
  int i = blockIdx.x * 256 + threadIdx.x;   // 2*6144
  int b = i / 6144, col = i % 6144;
  float a = bias[col];
  #pragma unroll
  for (int r = 0; r < 8; ++r) a += part[((size_t)r * 2 + b) * 6144 + col];
  mods[i] = a;
}

// ---------------------------------------------------------------------------
// RoPE table: ctab/stab[t*32+i] = cos/sin(pos[t] * 10000^(-i/32))
// ---------------------------------------------------------------------------
__global__ void __launch_bounds__(256) rope_table(const int* __restrict__ pos,
                                                  float* __restrict__ ct,
                                                  float* __restrict__ st)
{
  int idx = blockIdx.x * 256 + threadIdx.x;   // T*32 = 65536
  int t = idx >> 5, i = idx & 31;
  float freq = expf(-0.28782313662425575f * (float)i);  // ln(10000)/32
  float ang = (float)pos[t] * freq;
  ct[idx] = cosf(ang);
  st[idx] = sinf(ang);
}

// ---------------------------------------------------------------------------
// RMSNorm (no affine) + AdaLN modulate -> bf16.  One block per (b,t) row.
// ---------------------------------------------------------------------------
__global__ void __launch_bounds__(256) rmsmod(const float* __restrict__ x,
                                              const float* __restrict__ mods,
                                              u16* __restrict__ out,
                                              int shift_off, int scale_off)
{
  __shared__ float wsum[4];
  int row = blockIdx.x;            // b*2048 + t
  int b = row >> 11;
  const float4 v = ((const float4*)(x + (size_t)row * 1024))[threadIdx.x];
  float ss = v.x * v.x + v.y * v.y + v.z * v.z + v.w * v.w;
  #pragma unroll
  for (int m = 1; m < 64; m <<= 1) ss += __shfl_xor(ss, m);
  if ((threadIdx.x & 63) == 0) wsum[threadIdx.x >> 6] = ss;
  __syncthreads();
  float tot = wsum[0] + wsum[1] + wsum[2] + wsum[3];
  float rr = rsqrtf(tot * (1.f / 1024.f) + 1e-6f);
  const float* mb = mods + (size_t)b * 6144;
  int d0 = threadIdx.x * 4;
  ushort4 o;
  o.x = f2bf(v.x * rr * (1.f + mb[scale_off + d0 + 0]) + mb[shift_off + d0 + 0]);
  o.y = f2bf(v.y * rr * (1.f + mb[scale_off + d0 + 1]) + mb[shift_off + d0 + 1]);
  o.z = f2bf(v.z * rr * (1.f + mb[scale_off + d0 + 2]) + mb[shift_off + d0 + 2]);
  o.w = f2bf(v.w * rr * (1.f + mb[scale_off + d0 + 3]) + mb[shift_off + d0 + 3]);
  ((ushort4*)(out + (size_t)row * 1024))[threadIdx.x] = o;
}

// ---------------------------------------------------------------------------
// Weight transpose + cast: in f32 [R][C] -> out bf16 [C][R]
// ---------------------------------------------------------------------------
__global__ void __launch_bounds__(256) transpose_w(const float* __restrict__ in,
                                                   u16* __restrict__ out, int R, int C)
{
  __shared__ float t[32][33];
  int tx = threadIdx.x & 31, ty = threadIdx.x >> 5;
  int c0 = blockIdx.x * 32, r0 = blockIdx.y * 32;
  #pragma unroll
  for (int i = 0; i < 4; ++i) t[ty + 8 * i][tx] = in[(size_t)(r0 + ty + 8 * i) * C + c0 + tx];
  __syncthreads();
  #pragma unroll
  for (int i = 0; i < 4; ++i) out[(size_t)(c0 + ty + 8 * i) * R + r0 + tx] = f2bf(t[tx][ty + 8 * i]);
}

// ---------------------------------------------------------------------------
// V transpose: qkv bf16 [B,T,3D] (v slice) -> vt bf16 [B,H,Dh,T]
// ---------------------------------------------------------------------------
__global__ void __launch_bounds__(256) vtrans(const u16* __restrict__ qkv,
                                              u16* __restrict__ vt)
{
  __shared__ u16 tile[32][33];
  int tx = threadIdx.x & 31, ty = threadIdx.x >> 5;
  int t0 = blockIdx.x * 32;
  int d0 = blockIdx.y * 32;
  int bh = blockIdx.z; int b = bh >> 4, h = bh & 15;
  #pragma unroll
  for (int i = 0; i < 4; ++i) {
    int t = t0 + ty + 8 * i;
    tile[ty + 8 * i][tx] = qkv[((size_t)(b * 2048 + t)) * 3072 + 2048 + h * 64 + d0 + tx];
  }
  __syncthreads();
  #pragma unroll
  for (int i = 0; i < 4; ++i) {
    int d = d0 + ty + 8 * i;
    vt[((size_t)bh * 64 + d) * 2048 + t0 + tx] = tile[tx][ty + 8 * i];
  }
}

// ---------------------------------------------------------------------------
// GEMM (qkv): C[M,N] = A * Bt^T, bf16 out. r7-proven geometry: 128x128,
// BK=64, SINGLE-buffered 32KB LDS, 2 barriers/K-step, 8-chunk swizzle,
// slab-remapped blocks.
// ---------------------------------------------------------------------------
__global__ void __launch_bounds__(256) gemm_bt(const u16* __restrict__ A,
                                               const u16* __restrict__ Bt,
                                               int M, int N, int K,
                                               int SX, int SY,
                                               u16* __restrict__ outb)
{
  __shared__ __align__(16) u16 Ash[128 * 64];   // 16KB
  __shared__ __align__(16) u16 Bsh[128 * 64];   // 16KB
  const int tid = threadIdx.x;
  const int l = tid & 63, w = tid >> 6;
  int bx, by; slab_remap(SX, SY, bx, by);
  const int m0 = by * 128, n0 = bx * 128;
  const int wr = (w >> 1) * 64, wc = (w & 1) * 64;
  const int fr = l & 15, fg = l >> 4;
  const int sw = fr & 7;
  f32x4 acc[4][4] = {};

  for (int kt = 0; kt < K; kt += 64) {
    __syncthreads();
    #pragma unroll
    for (int p = 0; p < 4; ++p) {
      int slot = p * 256 + tid;           // 0..1023
      int r = slot >> 3, kp = slot & 7;
      int kpg = kp ^ (r & 7);             // pre-swizzled source chunk (rule #21)
      cp16(A + (size_t)(m0 + r) * K + kt + kpg * 8, Ash + slot * 8);
      cp16(Bt + (size_t)(n0 + r) * K + kt + kpg * 8, Bsh + slot * 8);
    }
    __syncthreads();
    #pragma unroll
    for (int kk = 0; kk < 2; ++kk) {
      const int coff = ((kk * 4 + fg) ^ sw) * 8;   // swizzled 16B chunk within row
      bf16x8 af[4], bfr[4];
      #pragma unroll
      for (int m = 0; m < 4; ++m) af[m] = *(const bf16x8*)(Ash + (wr + m * 16 + fr) * 64 + coff);
      #pragma unroll
      for (int n = 0; n < 4; ++n) bfr[n] = *(const bf16x8*)(Bsh + (wc + n * 16 + fr) * 64 + coff);
      #pragma unroll
      for (int m = 0; m < 4; ++m)
        #pragma unroll
        for (int n = 0; n < 4; ++n)
          acc[m][n] = mfma16(af[m], bfr[n], acc[m][n]);
    }
  }

  #pragma unroll
  for (int m = 0; m < 4; ++m)
  #pragma unroll
  for (int n = 0; n < 4; ++n)
  #pragma unroll
  for (int j = 0; j < 4; ++j) {
    int row = m0 + wr + m * 16 + fg * 4 + j;
    int col = n0 + wc + n * 16 + fr;
    outb[(size_t)row * N + col] = f2bf(acc[m][n][j]);
  }
}

// ---------------------------------------------------------------------------
// Skinny GEMM for N=1024 outputs (proj, w2): BM=64 x BN=128, BK=64, dbuf LDS,
// slab-remapped (params). EPI: 1 = res + gate*(C+bias); 4 = res + gate*C.
// ---------------------------------------------------------------------------
template<int EPI>
__global__ void __launch_bounds__(256) gemm_skinny(const u16* __restrict__ A,
                                                   const u16* __restrict__ Bt,
                                                   int M, int N, int K,
                                                   int SX, int SY,
                                                   const float* __restrict__ mods,
                                                   int gate_off,
                                                   const float* __restrict__ bias,
                                                   const float* __restrict__ res,
                                                   float* __restrict__ outf)
{
  __shared__ __align__(16) u16 Ash[2][64 * 64];    // 16KB
  __shared__ __align__(16) u16 Bsh[2][128 * 64];   // 32KB
  const int tid = threadIdx.x;
  const int l = tid & 63, w = tid >> 6;
  int bx, by; slab_remap(SX, SY, bx, by);
  const int m0 = by * 64, n0 = bx * 128;
  const int wr = (w >> 1) * 32, wc = (w & 1) * 64;
  const int fr = l & 15, fg = l >> 4;
  const int sw = fr & 7;
  const int nk = K >> 6;
  f32x4 acc[2][4] = {};

  auto stage = [&](int kt, int bsel) {
    #pragma unroll
    for (int p = 0; p < 2; ++p) {
      int slot = p * 256 + tid;            // 0..511 (A rows 0..63)
      int r = slot >> 3, kp = slot & 7;
      int kpg = kp ^ (r & 7);
      cp16(A + (size_t)(m0 + r) * K + kt + kpg * 8, &Ash[bsel][slot * 8]);
    }
    #pragma unroll
    for (int p = 0; p < 4; ++p) {
      int slot = p * 256 + tid;            // 0..1023 (B rows 0..127)
      int r = slot >> 3, kp = slot & 7;
      int kpg = kp ^ (r & 7);
      cp16(Bt + (size_t)(n0 + r) * K + kt + kpg * 8, &Bsh[bsel][slot * 8]);
    }
  };

  stage(0, 0);
  __syncthreads();

  for (int t = 0; t < nk; ++t) {
    if (t + 1 < nk) stage((t + 1) << 6, (t + 1) & 1);
    const u16* Ab = Ash[t & 1];
    const u16* Bb = Bsh[t & 1];
    #pragma unroll
    for (int kk = 0; kk < 2; ++kk) {
      const int coff = ((kk * 4 + fg) ^ sw) * 8;
      bf16x8 af[2], bfr[4];
      #pragma unroll
      for (int m = 0; m < 2; ++m) af[m] = *(const bf16x8*)(Ab + (wr + m * 16 + fr) * 64 + coff);
      #pragma unroll
      for (int n = 0; n < 4; ++n) bfr[n] = *(const bf16x8*)(Bb + (wc + n * 16 + fr) * 64 + coff);
      #pragma unroll
      for (int m = 0; m < 2; ++m)
        #pragma unroll
        for (int n = 0; n < 4; ++n)
          acc[m][n] = mfma16(af[m], bfr[n], acc[m][n]);
    }
    __syncthreads();   // drains stage(t+1) (hidden under compute) + WAR
  }

  #pragma unroll
  for (int m = 0; m < 2; ++m)
  #pragma unroll
  for (int n = 0; n < 4; ++n)
  #pragma unroll
  for (int j = 0; j < 4; ++j) {
    int row = m0 + wr + m * 16 + fg * 4 + j;
    int col = n0 + wc + n * 16 + fr;
    size_t idx = (size_t)row * N + col;
    float v = acc[m][n][j];
    int b = row >> 11;
    if (EPI == 1)
      outf[idx] = res[idx] + mods[(size_t)b * 6144 + gate_off + col] * (v + bias[col]);
    else
      outf[idx] = res[idx] + mods[(size_t)b * 6144 + gate_off + col] * v;
  }
}

// ---------------------------------------------------------------------------
// 1-barrier-per-tile counted-vmcnt SwiGLU GEMM (r18 best, 63.5us):
// BM=256, BN=128/product, BK=64, 8 waves, 128KB dbuf LDS, slab (11,2).
// Full next-tile prefetch (8 loads), WAIT_VM(8) (never 0), one s_barrier,
// then two unbarriered half-phases with compiler-scheduled lgkmcnt.
// ---------------------------------------------------------------------------
__global__ void __launch_bounds__(512) gemm_w13(const u16* __restrict__ A,
                                                const u16* __restrict__ B1t,
                                                const u16* __restrict__ B3t,
                                                u16* __restrict__ outb)
{
  const int K = 1024, N = 2816, NK = 16;   // K / 64
  __shared__ __align__(16) char smem[131072];  // [2][A 32KB | B1 16KB | B3 16KB]
  const int tid = threadIdx.x;             // 0..511
  const int l = tid & 63, w = tid >> 6;    // 8 waves
  const int wm = w >> 1, wn = w & 1;       // 4M x 2N
  int bx, by; slab_remap(11, 2, bx, by);
  const int m0 = by * 256, n0 = bx * 128;
  const int fr = l & 15, fg = l >> 4;

  const int r0 = tid >> 3, cl = tid & 7;
  const int cg = cl ^ (r0 & 7);
  const size_t aoffA0_0 = (size_t)(m0 + r0) * K + cg * 8;
  const size_t aoffA0_1 = (size_t)(m0 + 64 + r0) * K + cg * 8;
  const size_t aoffA1_0 = (size_t)(m0 + 128 + r0) * K + cg * 8;
  const size_t aoffA1_1 = (size_t)(m0 + 192 + r0) * K + cg * 8;
  const size_t boff_0   = (size_t)(n0 + r0) * K + cg * 8;
  const size_t boff_1   = (size_t)(n0 + 64 + r0) * K + cg * 8;
  const int lds0 = tid * 16, lds1 = (512 + tid) * 16;   // within a 16KB half

  const int co0 = ((0 * 4 + fg) ^ (fr & 7)) << 4;   // kk=0 chunk byte off
  const int co1 = ((1 * 4 + fg) ^ (fr & 7)) << 4;   // kk=1
  int rA[4], rB[4];
  #pragma unroll
  for (int m = 0; m < 4; ++m) rA[m] = (wm * 64 + m * 16 + fr) * 128;
  #pragma unroll
  for (int n = 0; n < 4; ++n) rB[n] = (wn * 64 + n * 16 + fr) * 128;

  f32x4 acc1[4][4] = {}, acc3[4][4] = {};

  auto stA0 = [&](int kt, int buf){
    char* d = smem + buf * 65536;
    cp16(A + aoffA0_0 + kt, d + lds0);
    cp16(A + aoffA0_1 + kt, d + lds1);
  };
  auto stA1 = [&](int kt, int buf){
    char* d = smem + buf * 65536 + 16384;
    cp16(A + aoffA1_0 + kt, d + lds0);
    cp16(A + aoffA1_1 + kt, d + lds1);
  };
  auto stB1 = [&](int kt, int buf){
    char* d = smem + buf * 65536 + 32768;
    cp16(B1t + boff_0 + kt, d + lds0);
    cp16(B1t + boff_1 + kt, d + lds1);
  };
  auto stB3 = [&](int kt, int buf){
    char* d = smem + buf * 65536 + 49152;
    cp16(B3t + boff_0 + kt, d + lds0);
    cp16(B3t + boff_1 + kt, d + lds1);
  };

  // prologue: tile 0 -> buffer 0 (8 loads in flight, steady-state invariant)
  stA0(0, 0); stA1(0, 0); stB1(0, 0); stB3(0, 0);

  for (int t = 0; t < NK; ++t) {
    const int buf = t & 1, nbuf = buf ^ 1;
    const int ktn = ((t + 1) & (NK - 1)) * 64;
    const char* Ab  = smem + buf * 65536;          // A0 | A1 contiguous 32KB
    const char* B1b = smem + buf * 65536 + 32768;
    const char* B3b = smem + buf * 65536 + 49152;

    // issue the FULL next-tile prefetch (8 loads -> 16 in flight)
    stA0(ktn, nbuf); stA1(ktn, nbuf); stB1(ktn, nbuf); stB3(ktn, nbuf);
    WAIT_VM(8);      // drains exactly tile t's 8 loads; t+1's stay in flight
    FENCE_BARRIER;   // all waves' tile-t data visible

    bf16x8 af0[4], af1[4];
    #pragma unroll
    for (int m = 0; m < 4; ++m) af0[m] = *(const bf16x8*)(Ab + rA[m] + co0);
    #pragma unroll
    for (int m = 0; m < 4; ++m) af1[m] = *(const bf16x8*)(Ab + rA[m] + co1);

    // ---- half-phase 1: acc1 (A x B1), kk=0 and kk=1 ----
    {
      bf16x8 b0[4], b1[4];
      #pragma unroll
      for (int n = 0; n < 4; ++n) b0[n] = *(const bf16x8*)(B1b + rB[n] + co0);
      #pragma unroll
      for (int n = 0; n < 4; ++n) b1[n] = *(const bf16x8*)(B1b + rB[n] + co1);
      __builtin_amdgcn_s_setprio(1);
      #pragma unroll
      for (int m = 0; m < 4; ++m)
        #pragma unroll
        for (int n = 0; n < 4; ++n) acc1[m][n] = mfma16(af0[m], b0[n], acc1[m][n]);
      #pragma unroll
      for (int m = 0; m < 4; ++m)
        #pragma unroll
        for (int n = 0; n < 4; ++n) acc1[m][n] = mfma16(af1[m], b1[n], acc1[m][n]);
      __builtin_amdgcn_s_setprio(0);
    }

    // ---- half-phase 2: acc3 (A x B3); A-frags still live ----
    {
      bf16x8 b0[4], b1[4];
      #pragma unroll
      for (int n = 0; n < 4; ++n) b0[n] = *(const bf16x8*)(B3b + rB[n] + co0);
      #pragma unroll
      for (int n = 0; n < 4; ++n) b1[n] = *(const bf16x8*)(B3b + rB[n] + co1);
      __builtin_amdgcn_s_setprio(1);
      #pragma unroll
      for (int m = 0; m < 4; ++m)
        #pragma unroll
        for (int n = 0; n < 4; ++n) acc3[m][n] = mfma16(af0[m], b0[n], acc3[m][n]);
      #pragma unroll
      for (int m = 0; m < 4; ++m)
        #pragma unroll
        for (int n = 0; n < 4; ++n) acc3[m][n] = mfma16(af1[m], b1[n], acc3[m][n]);
      __builtin_amdgcn_s_setprio(0);
    }
  }

  // epilogue: silu(acc1)*acc3, pairing in-thread; direct global store
  #pragma unroll
  for (int m = 0; m < 4; ++m)
  #pragma unroll
  for (int n = 0; n < 4; ++n)
  #pragma unroll
  for (int j = 0; j < 4; ++j) {
    int row = m0 + wm * 64 + m * 16 + fg * 4 + j;
    int col = n0 + wn * 64 + n * 16 + fr;
    float v1 = acc1[m][n][j];
    float v3 = acc3[m][n][j];
    float s = v1 / (1.f + __expf(-v1));
    outb[(size_t)row * N + col] = f2bf(s * v3);
  }
}

// ---------------------------------------------------------------------------
// qk-norm (per-head RMS, affine) + RoPE.
// qkv bf16 [B,T,3D] -> q/k bf16 [B,H,T,Dh]; q pre-scaled by log2(e)/sqrt(Dh).
// ---------------------------------------------------------------------------
__global__ void __launch_bounds__(256) qknorm_rope(const u16* __restrict__ qkv,
                                                   const float* __restrict__ lnq,
                                                   const float* __restrict__ lnk,
                                                   const float* __restrict__ ctab,
                                                   const float* __restrict__ stab,
                                                   u16* __restrict__ qo,
                                                   u16* __restrict__ ko)
{
  int r = blockIdx.x * 4 + (threadIdx.x >> 6);   // (b*2048 + t)*16 + h
  int l = threadIdx.x & 63;
  int h = r & 15, t = (r >> 4) & 2047, b = r >> 15;
  const u16* base = qkv + ((size_t)(b * 2048 + t)) * 3072 + h * 64 + l;
  float q = bf2f(base[0]);
  float k = bf2f(base[1024]);
  float sq = q * q, sk = k * k;
  #pragma unroll
  for (int m = 1; m < 64; m <<= 1) { sq += __shfl_xor(sq, m); sk += __shfl_xor(sk, m); }
  float rq = rsqrtf(sq * (1.f / 64.f) + 1e-6f);
  float rk = rsqrtf(sk * (1.f / 64.f) + 1e-6f);
  float yq = q * rq * lnq[l];
  float yk = k * rk * lnk[l];
  float cs = ctab[t * 32 + (l & 31)];
  float sn = stab[t * 32 + (l & 31)];
  float pq = __shfl_xor(yq, 32);
  float pk = __shfl_xor(yk, 32);
  float rotq = (l < 32) ? -pq : pq;
  float rotk = (l < 32) ? -pk : pk;
  float oq = (yq * cs + rotq * sn) * 0.1803368801111204f;  // (1/8)*log2(e)
  float ok = yk * cs + rotk * sn;
  size_t oidx = ((size_t)(b * 16 + h) * 2048 + t) * 64 + l;
  qo[oidx] = f2bf(oq);
  ko[oidx] = f2bf(ok);
}

// ---------------------------------------------------------------------------
// Flash attention, 32x32 swapped-QK^T, MAX-FREE softmax (|q.k|/8 <= 8 after
// qk-norm + norm-preserving RoPE -> exp2 args bounded; no running max).
// KVBLK=128, K/V dbuf in LDS via async global_load_lds; XOR-chunk swizzle
// staged on the GLOBAL source (rule #21). XCD-aware block remap.
// ---------------------------------------------------------------------------
__global__ void __launch_bounds__(256, 2) flash_attn(const u16* __restrict__ qg,
                                                     const u16* __restrict__ kg,
                                                     const u16* __restrict__ vtg,
                                                     u16* __restrict__ og)
{
  __shared__ __align__(16) char smem[65536];
  const int tid = threadIdx.x, l = tid & 63, w = tid >> 6;
  const int lq = l & 31, hi = l >> 5;
  const int swz = lq & 7;
  const int xcd = blockIdx.x & 7, slot = blockIdx.x >> 3;
  const int g = slot >> 4, qt = slot & 15;
  const int bh = g * 8 + xcd;
  const int h = bh & 15, b = bh >> 4;

  bf16x8 qf[4];
  {
    const u16* qp = qg + ((size_t)bh * 2048 + qt * 128 + w * 32 + lq) * 64 + hi * 8;
    #pragma unroll
    for (int ks = 0; ks < 4; ++ks) qf[ks] = *(const bf16x8*)(qp + ks * 16);
  }
  const u16* kgb = kg + (size_t)bh * 2048 * 64;
  const u16* vgb = vtg + (size_t)bh * 64 * 2048;

  auto stage = [&](int kv, int bsel) {
    #pragma unroll
    for (int p = 0; p < 4; ++p) {
      int s2 = p * 256 + tid;            // 0..1023
      int r = s2 >> 3, cl = s2 & 7;
      int cg = cl ^ (r & 7);
      cp16(kgb + (size_t)(kv + r) * 64 + cg * 8, smem + bsel * 16384 + s2 * 16);
    }
    #pragma unroll
    for (int p = 0; p < 4; ++p) {
      int s2 = p * 256 + tid;            // 0..1023
      int r = s2 >> 4, cl = s2 & 15;
      int cg = cl ^ (r & 7);
      cp16(vgb + (size_t)r * 2048 + kv + cg * 8, smem + 32768 + bsel * 16384 + s2 * 16);
    }
  };

  f32x16 ob0 = {}, ob1 = {};
  float l_run = 0.f;

  stage(0, 0);
  __syncthreads();

  for (int t = 0; t < 16; ++t) {
    const int cur = t & 1;
    stage(((t + 1) & 15) * 128, cur ^ 1);   // async prefetch next tile
    const char* Kb = smem + cur * 16384;
    const char* Vb = smem + 32768 + cur * 16384;

    #pragma unroll
    for (int ko = 0; ko < 128; ko += 64) {
      f32x16 s0 = {}, s1 = {};
      __builtin_amdgcn_s_setprio(1);
      #pragma unroll
      for (int ks = 0; ks < 4; ++ks) {
        const int c = hi + ks * 2;
        bf16x8 kf0 = *(const bf16x8*)(Kb + (ko + lq) * 128 + ((c ^ swz) << 4));
        bf16x8 kf1 = *(const bf16x8*)(Kb + (ko + 32 + lq) * 128 + ((c ^ swz) << 4));
        s0 = mfma32(kf0, qf[ks], s0);
        s1 = mfma32(kf1, qf[ks], s1);
      }
      __builtin_amdgcn_s_setprio(0);
      #pragma unroll
      for (int r = 0; r < 16; ++r) s0[r] = fexp2(s0[r]);
      #pragma unroll
      for (int r = 0; r < 16; ++r) s1[r] = fexp2(s1[r]);
      {
        float t0 = (s0[0] + s0[1]) + (s0[2] + s0[3]);
        float t1 = (s0[4] + s0[5]) + (s0[6] + s0[7]);
        float t2 = (s0[8] + s0[9]) + (s0[10] + s0[11]);
        float t3 = (s0[12] + s0[13]) + (s0[14] + s0[15]);
        float u0 = (s1[0] + s1[1]) + (s1[2] + s1[3]);
        float u1 = (s1[4] + s1[5]) + (s1[6] + s1[7]);
        float u2 = (s1[8] + s1[9]) + (s1[10] + s1[11]);
        float u3 = (s1[12] + s1[13]) + (s1[14] + s1[15]);
        float ls = ((t0 + t1) + (t2 + t3)) + ((u0 + u1) + (u2 + u3));
        float lo = ls;
        fswap(ls, lo);
        l_run += ls + lo;
      }
      uint32_t pw[16];
      {
        uint32_t x0 = cvtpk(s0[0], s0[1]),   y0 = cvtpk(s0[4], s0[5]);   uswap(x0, y0);
        uint32_t x1 = cvtpk(s0[2], s0[3]),   y1 = cvtpk(s0[6], s0[7]);   uswap(x1, y1);
        uint32_t x2 = cvtpk(s0[8], s0[9]),   y2 = cvtpk(s0[12], s0[13]); uswap(x2, y2);
        uint32_t x3 = cvtpk(s0[10], s0[11]), y3 = cvtpk(s0[14], s0[15]); uswap(x3, y3);
        pw[0] = x0; pw[1] = x1; pw[2] = y0; pw[3] = y1;
        pw[4] = x2; pw[5] = x3; pw[6] = y2; pw[7] = y3;
      }
      {
        uint32_t x0 = cvtpk(s1[0], s1[1]),   y0 = cvtpk(s1[4], s1[5]);   uswap(x0, y0);
        uint32_t x1 = cvtpk(s1[2], s1[3]),   y1 = cvtpk(s1[6], s1[7]);   uswap(x1, y1);
        uint32_t x2 = cvtpk(s1[8], s1[9]),   y2 = cvtpk(s1[12], s1[13]); uswap(x2, y2);
        uint32_t x3 = cvtpk(s1[10], s1[11]), y3 = cvtpk(s1[14], s1[15]); uswap(x3, y3);
        pw[8] = x0;  pw[9] = x1;  pw[10] = y0; pw[11] = y1;
        pw[12] = x2; pw[13] = x3; pw[14] = y2; pw[15] = y3;
      }
      __builtin_amdgcn_s_setprio(1);
      #pragma unroll
      for (int ks = 0; ks < 4; ++ks) {
        union { uint32_t u[4]; bf16x8 v; } pk_;
        pk_.u[0] = pw[ks * 4 + 0]; pk_.u[1] = pw[ks * 4 + 1];
        pk_.u[2] = pw[ks * 4 + 2]; pk_.u[3] = pw[ks * 4 + 3];
        const int c = (ko >> 3) + ks * 2 + hi;
        bf16x8 vf0 = *(const bf16x8*)(Vb + lq * 256 + ((c ^ swz) << 4));
        bf16x8 vf1 = *(const bf16x8*)(Vb + (32 + lq) * 256 + ((c ^ swz) << 4));
        ob0 = mfma32(vf0, pk_.v, ob0);
        ob1 = mfma32(vf1, pk_.v, ob1);
      }
      __builtin_amdgcn_s_setprio(0);
    }
    __syncthreads();
  }

  float invl = 1.0f / l_run;
  char* ob_base = smem + w * 4096 + lq * 128 + 8 * hi;
  #pragma unroll
  for (int g2 = 0; g2 < 4; ++g2) {
    uint2 t2;
    t2.x = cvtpk(ob0[g2 * 4 + 0] * invl, ob0[g2 * 4 + 1] * invl);
    t2.y = cvtpk(ob0[g2 * 4 + 2] * invl, ob0[g2 * 4 + 3] * invl);
    *(uint2*)(ob_base + ((g2 ^ (lq & 7)) << 4)) = t2;
    uint2 t3;
    t3.x = cvtpk(ob1[g2 * 4 + 0] * invl, ob1[g2 * 4 + 1] * invl);
    t3.y = cvtpk(ob1[g2 * 4 + 2] * invl, ob1[g2 * 4 + 3] * invl);
    *(uint2*)(ob_base + (((g2 + 4) ^ (lq & 7)) << 4)) = t3;
  }
  __syncthreads();
  #pragma unroll
  for (int i = 0; i < 4; ++i) {
    int idx = i * 256 + tid;
    int ww = idx >> 8, q = (idx >> 3) & 31, s = idx & 7;
    uint4 val = *(const uint4*)(smem + ww * 4096 + q * 128 + ((s ^ (q & 7)) << 4));
    int t = qt * 128 + ww * 32 + q;
    *(uint4*)(og + ((size_t)(b * 2048 + t)) * 1024 + h * 64 + s * 8) = val;
  }
}

// ---------------------------------------------------------------------------
extern "C" void kernel_launch(void* const* d_in, const int* in_sizes, int n_in,
                              void* d_out, int out_size, void* d_ws, size_t ws_size,
                              hipStream_t stream)
{
  (void)in_sizes; (void)n_in; (void)out_size; (void)ws_size;
  const float* x       = (const float*)d_in[0];
  const float* c       = (const float*)d_in[1];
  const int*   pos     = (const int*)d_in[2];
  const float* adaln_w = (const float*)d_in[3];
  const float* adaln_b = (const float*)d_in[4];
  const float* qkv_w   = (const float*)d_in[5];
  const float* lnq     = (const float*)d_in[6];
  const float* lnk     = (const float*)d_in[7];
  const float* proj_w  = (const float*)d_in[8];
  const float* proj_b  = (const float*)d_in[9];
  const float* w1_w    = (const float*)d_in[10];
  const float* w3_w    = (const float*)d_in[11];
  const float* w2_w    = (const float*)d_in[12];
  float* out = (float*)d_out;

  char* ws = (char*)d_ws;
  size_t off = 0;
  auto alloc = [&](size_t bytes) -> char* {
    char* p = ws + off; off += (bytes + 255) & ~(size_t)255; return p;
  };
  float* part    = (float*)alloc((size_t)8 * 2 * 6144 * 4);
  float* mods    = (float*)alloc((size_t)2 * 6144 * 4);
  float* ctab    = (float*)alloc((size_t)2048 * 32 * 4);
  float* stab    = (float*)alloc((size_t)2048 * 32 * 4);
  u16* qkv_wt    = (u16*)alloc((size_t)3072 * 1024 * 2);
  u16* proj_wt   = (u16*)alloc((size_t)1024 * 1024 * 2);
  u16* w1_wt     = (u16*)alloc((size_t)2816 * 1024 * 2);
  u16* w3_wt     = (u16*)alloc((size_t)2816 * 1024 * 2);
  u16* w2_wt     = (u16*)alloc((size_t)1024 * 2816 * 2);
  float* x1      = (float*)alloc((size_t)4096 * 1024 * 4);
  u16* attn_bf   = (u16*)alloc((size_t)4096 * 1024 * 2);
  char* pool = ws + off;   // phase-aliased region
  // phase A
  u16* xmod_bf   = (u16*)(pool);
  u16* qkv_bf    = (u16*)(pool + 8388608);
  u16* q_bf      = (u16*)(pool + 33554432);
  u16* k_bf      = (u16*)(pool + 41943040);
  u16* vt_bf     = (u16*)(pool + 50331648);
  // phase B (aliases phase A, which is dead by then)
  u16* h_bf      = (u16*)(pool);
  u16* hidden_bf = (u16*)(pool + 31457280);

  adaln1<<<dim3(24, 8), 256, 0, stream>>>(c, adaln_w, part);
  adaln2<<<48, 256, 0, stream>>>(part, adaln_b, mods);
  rope_table<<<256, 256, 0, stream>>>(pos, ctab, stab);
  rmsmod<<<4096, 256, 0, stream>>>(x, mods, xmod_bf, 0, 1024);
  transpose_w<<<dim3(96, 32), 256, 0, stream>>>(qkv_w, qkv_wt, 1024, 3072);
  transpose_w<<<dim3(32, 32), 256, 0, stream>>>(proj_w, proj_wt, 1024, 1024);
  transpose_w<<<dim3(88, 32), 256, 0, stream>>>(w1_w, w1_wt, 1024, 2816);
  transpose_w<<<dim3(88, 32), 256, 0, stream>>>(w3_w, w3_wt, 1024, 2816);
  transpose_w<<<dim3(32, 88), 256, 0, stream>>>(w2_w, w2_wt, 2816, 1024);

  gemm_bt<<<dim3(24, 32), 256, 0, stream>>>(xmod_bf, qkv_wt, 4096, 3072, 1024, 6, 8, qkv_bf);
  qknorm_rope<<<16384, 256, 0, stream>>>(qkv_bf, lnq, lnk, ctab, stab, q_bf, k_bf);
  vtrans<<<dim3(64, 2, 32), 256, 0, stream>>>(qkv_bf, vt_bf);
  flash_attn<<<512, 256, 0, stream>>>(q_bf, k_bf, vt_bf, attn_bf);
  gemm_skinny<1><<<dim3(8, 64), 256, 0, stream>>>(attn_bf, proj_wt, 4096, 1024, 1024,
                                                  2, 4, mods, 2048, proj_b, x, x1);
  rmsmod<<<4096, 256, 0, stream>>>(x1, mods, h_bf, 3072, 4096);
  gemm_w13<<<dim3(22, 16), 512, 0, stream>>>(h_bf, w1_wt, w3_wt, hidden_bf);
  gemm_skinny<4><<<dim3(8, 64), 256, 0, stream>>>(hidden_bf, w2_wt, 4096, 1024, 2816,
                                                  2, 4, mods, 5120, nullptr, x1, out);
}